// Round 1
// baseline (118.386 us; speedup 1.0000x reference)
//
#include <hip/hip_runtime.h>

// Problem constants (fixed by setup_inputs): image (4,3,1024,1024) f32,
// pMtrx (4,2,3) f32, W=H=1024, align_corners=True.
//
// Forward-pass collapse: g0 = stop_gradient(grid) => grid - g0 == 0 exactly,
// so out = transpose(bilinear_sample(image, affine_grid(pMtrx,...)), (0,3,1,2)).
// The NUM_AUX noisy samples / 2x2 solves contribute exactly 0 to the output.

#define B_  4
#define C_  3
#define HI  1024
#define WI  1024
#define HO  1024   // = W (h_out)
#define WO  1024   // = H (w_out)

__global__ __launch_bounds__(256) void warp_bilinear_kernel(
    const float* __restrict__ image,   // (B, C, HI, WI)
    const float* __restrict__ theta,   // (B, 2, 3)
    float* __restrict__ out)           // (B, C, HO, WO)
{
    const int idx = blockIdx.x * blockDim.x + threadIdx.x;
    const int w = idx & (WO - 1);          // fastest dim
    const int h = (idx >> 10) & (HO - 1);
    const int b = idx >> 20;

    // base coords: linspace(-1, 1, N) with align_corners
    const float xs = -1.0f + 2.0f * (float)w / (float)(WO - 1);
    const float ys = -1.0f + 2.0f * (float)h / (float)(HO - 1);

    const float* t = theta + b * 6;
    const float x = t[0] * xs + t[1] * ys + t[2];
    const float y = t[3] * xs + t[4] * ys + t[5];

    // align_corners=True unnormalize
    const float ix = (x + 1.0f) * 0.5f * (float)(WI - 1);
    const float iy = (y + 1.0f) * 0.5f * (float)(HI - 1);

    const float x0f = floorf(ix);
    const float y0f = floorf(iy);
    const float wx1 = ix - x0f;
    const float wy1 = iy - y0f;
    const float wx0 = 1.0f - wx1;
    const float wy0 = 1.0f - wy1;

    const int x0 = (int)x0f;
    const int y0 = (int)y0f;
    const int x1 = x0 + 1;
    const int y1 = y0 + 1;

    const bool vx0 = (x0 >= 0) && (x0 <= WI - 1);
    const bool vx1 = (x1 >= 0) && (x1 <= WI - 1);
    const bool vy0 = (y0 >= 0) && (y0 <= HI - 1);
    const bool vy1 = (y1 >= 0) && (y1 <= HI - 1);

    const int xc0 = min(max(x0, 0), WI - 1);
    const int xc1 = min(max(x1, 0), WI - 1);
    const int yc0 = min(max(y0, 0), HI - 1);
    const int yc1 = min(max(y1, 0), HI - 1);

    const float w00 = wx0 * wy0 * ((vx0 && vy0) ? 1.0f : 0.0f);
    const float w10 = wx1 * wy0 * ((vx1 && vy0) ? 1.0f : 0.0f);
    const float w01 = wx0 * wy1 * ((vx0 && vy1) ? 1.0f : 0.0f);
    const float w11 = wx1 * wy1 * ((vx1 && vy1) ? 1.0f : 0.0f);

    const int o00 = yc0 * WI + xc0;
    const int o10 = yc0 * WI + xc1;
    const int o01 = yc1 * WI + xc0;
    const int o11 = yc1 * WI + xc1;

    const float* imgb = image + (size_t)b * (C_ * HI * WI);
    float* ob = out + (size_t)b * (C_ * HO * WO) + h * WO + w;

#pragma unroll
    for (int c = 0; c < C_; ++c) {
        const float* p = imgb + c * (HI * WI);
        const float v = p[o00] * w00 + p[o10] * w10 + p[o01] * w01 + p[o11] * w11;
        ob[c * (HO * WO)] = v;
    }
}

extern "C" void kernel_launch(void* const* d_in, const int* in_sizes, int n_in,
                              void* d_out, int out_size, void* d_ws, size_t ws_size,
                              hipStream_t stream) {
    const float* image = (const float*)d_in[0];
    const float* theta = (const float*)d_in[1];
    // d_in[2] = W, d_in[3] = H (device ints) — fixed at 1024, baked in.
    float* out = (float*)d_out;

    const int total = B_ * HO * WO;          // one thread per (b,h,w)
    const int block = 256;
    const int grid = total / block;          // 4*1024*1024/256 = 16384
    warp_bilinear_kernel<<<grid, block, 0, stream>>>(image, theta, out);
}